// Round 13
// baseline (183.037 us; speedup 1.0000x reference)
//
#include <hip/hip_runtime.h>
#include <hip/hip_bf16.h>

// B=2, IMG_DIM=VOXEL_DIM=QK_DIM=256, H=W=64, N=4096.
// Inputs/outputs FP32; internal GEMMs bf16 MFMA (16x16x32).
// Pt layout: BLOCKED [b][qt][pt][128 q][128 p], tile = 32 KB contiguous.
// R13 = R12/R9 + ONE change: proj g==0 epilogue writes Q/Kt via LDS
// transpose with coalesced 1KB stores (was 2B scalar scatter).

typedef __hip_bfloat16 bf16;
typedef __attribute__((ext_vector_type(8))) short bf16x8;   // 8 bf16 = 4 VGPRs
typedef __attribute__((ext_vector_type(4))) float f32x4;

#define AS1 __attribute__((address_space(1)))
#define AS3 __attribute__((address_space(3)))

__device__ __forceinline__ void gld_lds16(const bf16* g, bf16* s) {
    // async global->LDS, 16B/lane; LDS dst = wave-uniform base + lane*16
    __builtin_amdgcn_global_load_lds((const AS1 void*)g, (AS3 void*)s, 16, 0, 0);
}

// ---------------------------------------------------------------------------
// Kernel 1 (v4): projections. 512 blocks: blk = s*256 + b*128 + g*64 + ntile.
// W staged through LDS per K-slab with fully-coalesced fp32 loads + XOR
// swizzle (R8-verified ~11 µs win). NEW (this round): g==0 (Q/Kt) epilogue
// transposes acc through XT and stores the contiguous 64x256 tile with
// 1KB-contiguous wave-stores; g==1 (V) path untouched (R10 showed its
// restructuring regresses).
// ---------------------------------------------------------------------------
__global__ __launch_bounds__(256) void proj_kernel(
    const float* __restrict__ img, const float* __restrict__ pc,
    const float* __restrict__ Wq,  const float* __restrict__ bq,
    const float* __restrict__ Wk,  const float* __restrict__ bk,
    const float* __restrict__ Wvi, const float* __restrict__ bvi,
    const float* __restrict__ Wvp, const float* __restrict__ bvp,
    bf16* __restrict__ Qw, bf16* __restrict__ Ktw, bf16* __restrict__ Vall)
{
    __shared__ __align__(16) bf16 XT[64][264];    // [pos][cin], +8 pad (33 KB)
    __shared__ __align__(16) bf16 Wst[256 * 32];  // swizzled W slab (16 KB)

    const int blk = blockIdx.x;
    const int s   = blk >> 8;
    const int b   = (blk >> 7) & 1;
    const int g   = (blk >> 6) & 1;
    const int n0  = (blk & 63) * 64;
    const int tid = threadIdx.x;

    if (s == 0) {
        const float* src = img + b * 1048576;                 // [256][4096]
        for (int k = 0; k < 16; k++) {
            const int i = tid + k * 256;
            const int cin = i >> 4, nl4 = (i & 15) * 4;
            const float4 v = *(const float4*)&src[cin * 4096 + n0 + nl4];
            XT[nl4 + 0][cin] = __float2bfloat16(v.x);
            XT[nl4 + 1][cin] = __float2bfloat16(v.y);
            XT[nl4 + 2][cin] = __float2bfloat16(v.z);
            XT[nl4 + 3][cin] = __float2bfloat16(v.w);
        }
    } else {
        // pc[b][d][h][w][c]: ch = c*16+d, flat = d*65536 + n*16 + c
        const float* src = pc + b * 1048576;
        for (int k = 0; k < 16; k++) {
            const int d = k, u = tid;
            const int nl = u >> 2, c4 = (u & 3) * 4;
            const float4 v = *(const float4*)&src[d * 65536 + (n0 + nl) * 16 + c4];
            XT[nl][(c4 + 0) * 16 + d] = __float2bfloat16(v.x);
            XT[nl][(c4 + 1) * 16 + d] = __float2bfloat16(v.y);
            XT[nl][(c4 + 2) * 16 + d] = __float2bfloat16(v.z);
            XT[nl][(c4 + 3) * 16 + d] = __float2bfloat16(v.w);
        }
    }

    const float* W = s ? (g ? Wvp : Wk) : (g ? Wvi : Wq);
    const float* Bv = s ? (g ? bvp : bk) : (g ? bvi : bq);

    const int wv = tid >> 6, lane = tid & 63, l16 = lane & 15, quad = lane >> 4;
    const int ob = wv * 64;

    f32x4 acc[4][4] = {};

    for (int ks = 0; ks < 8; ks++) {
        const int k0 = ks * 32;
        // ---- stage W slab [256 rows][32 k] -> Wst (swizzled), coalesced ----
        __syncthreads();                          // prev frag reads done
        for (int j = 0; j < 8; j++) {
            const int idx = j * 256 + tid;
            const int row = idx >> 3, c4 = (idx & 7) * 4;
            const float4 v = *(const float4*)&W[row * 256 + k0 + c4];
            bf16 t4[4];
            t4[0] = __float2bfloat16(v.x); t4[1] = __float2bfloat16(v.y);
            t4[2] = __float2bfloat16(v.z); t4[3] = __float2bfloat16(v.w);
            const int sl = (c4 >> 3) ^ ((row >> 1) & 3);
            *(uint2*)&Wst[row * 32 + sl * 8 + (c4 & 4)] = *(const uint2*)t4;
        }
        __syncthreads();

        bf16x8 af[4], wf[4];
        for (int ti = 0; ti < 4; ti++)
            af[ti] = *(const bf16x8*)&XT[ti * 16 + l16][k0 + quad * 8];
        for (int tj = 0; tj < 4; tj++) {
            const int rw = ob + tj * 16 + l16;
            wf[tj] = *(const bf16x8*)&Wst[rw * 32 + (quad ^ ((rw >> 1) & 3)) * 8];
        }
        for (int ti = 0; ti < 4; ti++)
            for (int tj = 0; tj < 4; tj++)
                acc[ti][tj] = __builtin_amdgcn_mfma_f32_16x16x32_bf16(af[ti], wf[tj], acc[ti][tj], 0, 0, 0);
    }

    if (g == 0) {
        // Q/Kt flat [n][256]: the 64x256 tile is one contiguous 32KB region.
        // Transpose through XT (padded), then 1KB-contiguous wave-stores.
        bf16* D1 = (s ? Ktw : Qw) + b * (4096 * 256) + n0 * 256;
        __syncthreads();                                      // XT frag reads done
        for (int tj = 0; tj < 4; tj++) {
            const int o = ob + tj * 16 + l16;
            const float bias = Bv[o];
            for (int ti = 0; ti < 4; ti++) {
                const int nl = ti * 16 + quad * 4;            // D row = quad*4+r
                for (int r = 0; r < 4; r++)
                    XT[nl + r][o] = __float2bfloat16(acc[ti][tj][r] + bias);
            }
        }
        __syncthreads();
        for (int j = 0; j < 8; j++) {
            const int idx = j * 256 + tid;                    // 16B slot id
            const int row = idx >> 5, col = (idx & 31) * 8;
            *(bf16x8*)&D1[row * 256 + col] = *(const bf16x8*)&XT[row][col];
        }
    } else {
        bf16* D2 = Vall + b * (512 * 4096) + (s ? 256 * 4096 : 0);  // [c'][p]
        for (int tj = 0; tj < 4; tj++) {
            const int o = ob + tj * 16 + l16;
            const float bias = Bv[o];
            for (int ti = 0; ti < 4; ti++) {
                const int nl = ti * 16 + quad * 4;
                bf16 pv[4];
                for (int r = 0; r < 4; r++)
                    pv[r] = __float2bfloat16(acc[ti][tj][r] + bias);
                *(uint2*)&D2[o * 4096 + n0 + nl] = *(const uint2*)pv;
            }
        }
    }
}

// ---------------------------------------------------------------------------
// Kernel 2 (v3): S^T tiles: A=Kt (p rows), B=Q (q rows), K=256.
// gld_lds + dbuf + counted vmcnt + XOR swizzle; blocked Pt store.
// ---------------------------------------------------------------------------
__global__ __launch_bounds__(256, 4) void attn_s_kernel(
    const bf16* __restrict__ Qw, const bf16* __restrict__ Ktw,
    bf16* __restrict__ Pt, float* __restrict__ Lpart)
{
    // per buffer: Kt-tile 128x32 @ 0 (8KB), Q-tile 128x32 @ 4096 (8KB)
    __shared__ __align__(16) bf16 smem[2][8192];              // 32 KB

    const int b  = blockIdx.z;
    const int q0 = blockIdx.y * 128;
    const int p0 = blockIdx.x * 128;
    const bf16* Aq = Qw  + b * (4096 * 256);
    const bf16* Ak = Ktw + b * (4096 * 256);

    const int tid = threadIdx.x;
    const int wv = tid >> 6, lane = tid & 63, l16 = lane & 15, quad = lane >> 4;
    const int wr = wv >> 1, wc = wv & 1;                      // wr: p-half, wc: q-half

    // swizzled fragment-read offsets (bf16 units), constant over ks
    int aoff[4], boff[4];
    for (int t = 0; t < 4; t++) {
        const int rowa = wr * 64 + t * 16 + l16;              // p row
        aoff[t] = rowa * 32 + (quad ^ ((rowa >> 1) & 3)) * 8;
        const int rowb = wc * 64 + t * 16 + l16;              // q row
        boff[t] = rowb * 32 + (quad ^ ((rowb >> 1) & 3)) * 8;
    }

    // staging: 512 16B-slots per tile; thread t covers slots t and t+256
    const int arow0 = tid >> 2;                               // rows 0..63
    const int kswz = ((tid & 3) ^ ((arow0 >> 1) & 3)) * 8;    // same for row+64
    const bf16* Ag0 = Ak + (p0 + arow0) * 256 + kswz;
    const bf16* Ag1 = Ak + (p0 + 64 + arow0) * 256 + kswz;
    const bf16* Bg0 = Aq + (q0 + arow0) * 256 + kswz;
    const bf16* Bg1 = Aq + (q0 + 64 + arow0) * 256 + kswz;

    f32x4 acc[4][4] = {};

#define SSTAGE(buf, ks)                                                 \
    do {                                                                \
        const int _k = (ks) * 32;                                       \
        bf16* _s = &smem[(buf)][0];                                     \
        gld_lds16(Ag0 + _k, _s + tid * 8);                              \
        gld_lds16(Ag1 + _k, _s + 2048 + tid * 8);                       \
        gld_lds16(Bg0 + _k, _s + 4096 + tid * 8);                       \
        gld_lds16(Bg1 + _k, _s + 6144 + tid * 8);                       \
    } while (0)

    SSTAGE(0, 0);
    int cur = 0;
    for (int ks = 0; ks < 8; ks++) {
        if (ks + 1 < 8) {
            SSTAGE(cur ^ 1, ks + 1);
            asm volatile("s_waitcnt vmcnt(4)" ::: "memory");  // cur's 4 landed
        } else {
            asm volatile("s_waitcnt vmcnt(0)" ::: "memory");
        }
        __builtin_amdgcn_s_barrier();                         // all waves' cur landed
        __builtin_amdgcn_sched_barrier(0);

        const bf16* As_ = &smem[cur][0];
        const bf16* Bs_ = &smem[cur][4096];
        bf16x8 af[4], bfr[4];
        for (int t = 0; t < 4; t++) af[t]  = *(const bf16x8*)&As_[aoff[t]];
        for (int t = 0; t < 4; t++) bfr[t] = *(const bf16x8*)&Bs_[boff[t]];
        __builtin_amdgcn_s_setprio(1);
        for (int ti = 0; ti < 4; ti++)
            for (int tj = 0; tj < 4; tj++)
                acc[ti][tj] = __builtin_amdgcn_mfma_f32_16x16x32_bf16(af[ti], bfr[tj], acc[ti][tj], 0, 0, 0);
        __builtin_amdgcn_s_setprio(0);

        asm volatile("s_waitcnt lgkmcnt(0)" ::: "memory");    // LDS reads retired
        __builtin_amdgcn_s_barrier();                         // safe to overwrite cur
        cur ^= 1;
    }
#undef SSTAGE

    __syncthreads();                                          // staging done; reuse LDS

    // ---- exp + LDS transpose (swizzled [128 q][128 p]) + L-partials ----
    bf16* T = &smem[0][0];                                    // 16384 bf16 = 32 KB
    const int strip = blockIdx.x * 2 + wr;                    // p strip of 64
    for (int tj = 0; tj < 4; tj++) {
        const int ql = wc * 64 + tj * 16 + l16;               // local q
        const int sw = (ql & 7) << 3;
        float partial = 0.0f;
        for (int ti = 0; ti < 4; ti++) {
            const int pb = wr * 64 + ti * 16 + quad * 4;      // local p base
            bf16 pv[4];
            for (int r = 0; r < 4; r++) {
                const float e = __expf(fminf(acc[ti][tj][r], 80.0f));
                partial += e;
                pv[r] = __float2bfloat16(e);
            }
            *(uint2*)&T[ql * 128 + (pb ^ sw)] = *(const uint2*)pv;
        }
        partial += __shfl_xor(partial, 16);
        partial += __shfl_xor(partial, 32);
        if (lane < 16)
            Lpart[(size_t)(b * 4096 + q0 + ql) * 64 + strip] = partial;
    }
    __syncthreads();

    // ---- coalesced blocked store: tile 32 KB contiguous ----
    bf16* Ptile = Pt + (size_t)((b * 32 + (q0 >> 7)) * 32 + (p0 >> 7)) * 16384;
    for (int j = 0; j < 8; j++) {
        const int qr = wv * 32 + j * 4 + (lane >> 4);         // local q row
        const int pcm = (lane & 15) * 8;                      // local p chunk
        const bf16x8 v = *(const bf16x8*)&T[qr * 128 + (pcm ^ ((qr & 7) << 3))];
        *(bf16x8*)&Ptile[qr * 128 + pcm] = v;                 // 1KB contig/instr
    }
}

// ---------------------------------------------------------------------------
// Kernel 2b: Linv[b][q] = 1 / sum_strip Lpart  (8192 rows)
// ---------------------------------------------------------------------------
__global__ __launch_bounds__(256) void lred_kernel(
    const float* __restrict__ Lpart, float* __restrict__ Linv)
{
    const int row = blockIdx.x * 256 + threadIdx.x;           // [0, 8192)
    const float4* lp = (const float4*)&Lpart[(size_t)row * 64];
    float s = 0.0f;
    for (int i = 0; i < 16; i++) {
        const float4 v = lp[i];
        s += v.x + v.y + v.z + v.w;
    }
    Linv[row] = 1.0f / fmaxf(s, 1e-30f);
}

// ---------------------------------------------------------------------------
// Kernel 3 (v7): O = Vall.Pt^T (NT, K=4096) * Linv[q].
// 128c x 128q, 256 blocks, 2 K-groups, quad-buffered counted-vmcnt pipeline,
// XOR + XCD swizzles, blocked-Pt B reads, deterministic combine.
// ---------------------------------------------------------------------------
__global__ __launch_bounds__(512, 2) void attn_o_kernel(
    const bf16* __restrict__ Vall, const bf16* __restrict__ Pt,
    const float* __restrict__ Linv, float* __restrict__ out)
{
    // [grp][buf]: As 128x32 @ 0 (4096 elems), Bs 128x32 @ 4096
    __shared__ __align__(16) bf16 smem[2][4][8192];           // 128 KB

    const int orig = blockIdx.x;
    const int L = (orig & 7) * 32 + (orig >> 3);              // XCD chunk swizzle
    const int b   = L >> 7;
    const int rem = L & 127;
    const int c0  = (rem & 3) * 128;
    const int q0  = (rem >> 2) * 128;

    const bf16* A  = Vall + (size_t)b * 512 * 4096;
    const bf16* Bt = Pt + (size_t)((b * 32 + (q0 >> 7)) * 32) * 16384;

    const int tid = threadIdx.x;
    const int grp = tid >> 8;                                 // K-split group (2)
    const int t8  = tid & 255;
    const int wv = t8 >> 6, lane = t8 & 63, l16 = lane & 15, quad = lane >> 4;
    const int wr = wv >> 1, wc = wv & 1;                      // 64c x 64q wave tile

    // swizzled fragment-read offsets (bf16 units), constant over ks
    int aoff[4], boff[4];
    for (int t = 0; t < 4; t++) {
        const int rowa = wr * 64 + t * 16 + l16;
        aoff[t] = rowa * 32 + (quad ^ ((rowa >> 1) & 3)) * 8;
        const int rowb = wc * 64 + t * 16 + l16;
        boff[t] = rowb * 32 + (quad ^ ((rowb >> 1) & 3)) * 8;
    }

    const int arow = t8 >> 2;                                 // staged row (local)
    const int kswz = ((t8 & 3) ^ ((arow >> 1) & 3)) * 8;      // pre-swizzled k chunk
    const bf16* Ag0 = A + (c0 + arow) * 4096 + kswz;
    const bf16* Ag1 = A + (c0 + 64 + arow) * 4096 + kswz;

    f32x4 acc[4][4] = {};

#define STAGE(buf, ks)                                                  \
    do {                                                                \
        const int _kk = grp * 2048 + (ks) * 32;                         \
        bf16* _s = &smem[grp][(buf)][0];                                \
        gld_lds16(Ag0 + _kk, _s + t8 * 8);                              \
        gld_lds16(Ag1 + _kk, _s + 2048 + t8 * 8);                       \
        const bf16* _bp = Bt + (size_t)(_kk >> 7) * 16384               \
                          + arow * 128 + (_kk & 127) + kswz;            \
        gld_lds16(_bp, _s + 4096 + t8 * 8);                             \
        gld_lds16(_bp + 8192, _s + 6144 + t8 * 8);                      \
    } while (0)

    STAGE(0, 0);
    STAGE(1, 1);
    STAGE(2, 2);
    for (int ks = 0; ks < 64; ks++) {
        // depth-4 counted prefetch: consumed stage ks was issued 3 iters ago
        if (ks + 3 < 64) {
            STAGE((ks + 3) & 3, ks + 3);
            asm volatile("s_waitcnt vmcnt(12)" ::: "memory"); // stage ks landed
        } else if (ks + 2 < 64) {
            asm volatile("s_waitcnt vmcnt(8)" ::: "memory");
        } else if (ks + 1 < 64) {
            asm volatile("s_waitcnt vmcnt(4)" ::: "memory");
        } else {
            asm volatile("s_waitcnt vmcnt(0)" ::: "memory");
        }
        __builtin_amdgcn_s_barrier();                         // all waves' stage ks landed
        __builtin_amdgcn_sched_barrier(0);

        const bf16* As_ = &smem[grp][ks & 3][0];
        const bf16* Bs_ = &smem[grp][ks & 3][4096];
        bf16x8 af[4], bfr[4];
        for (int t = 0; t < 4; t++) af[t]  = *(const bf16x8*)&As_[aoff[t]];
        for (int t = 0; t < 4; t++) bfr[t] = *(const bf16x8*)&Bs_[boff[t]];
        __builtin_amdgcn_s_setprio(1);
        for (int ti = 0; ti < 4; ti++)
            for (int tj = 0; tj < 4; tj++)
                acc[ti][tj] = __builtin_amdgcn_mfma_f32_16x16x32_bf16(af[ti], bfr[tj], acc[ti][tj], 0, 0, 0);
        __builtin_amdgcn_s_setprio(0);

        asm volatile("s_waitcnt lgkmcnt(0)" ::: "memory");    // LDS reads retired
        __builtin_amdgcn_s_barrier();                         // safe to overwrite buf (ks+4)&3
    }
#undef STAGE

    __syncthreads();                                          // full fence before LDS reuse

    // Deterministic cross-group combine in LDS (reuses staging space).
    float* comb = (float*)&smem[0][0][0];                     // [128 c][128 q] fp32 = 64 KB
    if (grp == 0) {
        for (int ti = 0; ti < 4; ti++)
            for (int tj = 0; tj < 4; tj++)
                for (int r = 0; r < 4; r++)
                    comb[(wr * 64 + ti * 16 + quad * 4 + r) * 128 + wc * 64 + tj * 16 + l16]
                        = acc[ti][tj][r];
    }
    __syncthreads();
    if (grp == 1) {
        for (int ti = 0; ti < 4; ti++)
            for (int tj = 0; tj < 4; tj++)
                for (int r = 0; r < 4; r++)
                    comb[(wr * 64 + ti * 16 + quad * 4 + r) * 128 + wc * 64 + tj * 16 + l16]
                        += acc[ti][tj][r];
    }
    __syncthreads();

    // All 512 threads: scale by Linv[q], store one c-row x 32 q segment.
    const int cl = tid >> 2, qb = (tid & 3) * 32;
    const int c_ = c0 + cl;
    const size_t base = (c_ < 256)
        ? ((size_t)b * 1048576 + (size_t)c_ * 4096)
        : (2097152u + (size_t)b * 1048576 + (size_t)(c_ - 256) * 4096);
    for (int j = 0; j < 8; j++) {
        const float4 v = *(const float4*)&comb[cl * 128 + qb + j * 4];
        const float4 l = *(const float4*)&Linv[b * 4096 + q0 + qb + j * 4];
        float4 o;
        o.x = v.x * l.x; o.y = v.y * l.y; o.z = v.z * l.z; o.w = v.w * l.w;
        *(float4*)&out[base + q0 + qb + j * 4] = o;
    }
}

// ---------------------------------------------------------------------------
// ws: [0,4)MB Q | [4,8)MB Kt | [8,16)MB Vall | [16,80)MB Pt (blocked) |
//     [80,82)MB Lpart fp32 [2][4096][64] | [82MB,+32KB) Linv fp32 [2][4096]
// ---------------------------------------------------------------------------
extern "C" void kernel_launch(void* const* d_in, const int* in_sizes, int n_in,
                              void* d_out, int out_size, void* d_ws, size_t ws_size,
                              hipStream_t stream)
{
    const float* img = (const float*)d_in[0];
    const float* pc  = (const float*)d_in[1];
    const float* Wq  = (const float*)d_in[2];
    const float* bq  = (const float*)d_in[3];
    const float* Wk  = (const float*)d_in[4];
    const float* bk  = (const float*)d_in[5];
    const float* Wvi = (const float*)d_in[6];
    const float* bvi = (const float*)d_in[7];
    const float* Wvp = (const float*)d_in[8];
    const float* bvp = (const float*)d_in[9];

    char* ws = (char*)d_ws;
    bf16*  Qw    = (bf16*)(ws);
    bf16*  Ktw   = (bf16*)(ws + (4ull  << 20));
    bf16*  Vall  = (bf16*)(ws + (8ull  << 20));
    bf16*  Pt    = (bf16*)(ws + (16ull << 20));
    float* Lpart = (float*)(ws + (80ull << 20));
    float* Linv  = (float*)(ws + (82ull << 20));

    proj_kernel<<<512, 256, 0, stream>>>(img, pc, Wq, bq, Wk, bk,
                                         Wvi, bvi, Wvp, bvp, Qw, Ktw, Vall);
    attn_s_kernel<<<dim3(32, 32, 2), 256, 0, stream>>>(Qw, Ktw, Pt, Lpart);
    lred_kernel<<<32, 256, 0, stream>>>(Lpart, Linv);
    attn_o_kernel<<<256, 512, 0, stream>>>(Vall, Pt, Linv, (float*)d_out);
}

// Round 14
// 181.591 us; speedup vs baseline: 1.0080x; 1.0080x over previous
//
#include <hip/hip_runtime.h>
#include <hip/hip_bf16.h>

// B=2, IMG_DIM=VOXEL_DIM=QK_DIM=256, H=W=64, N=4096.
// Inputs/outputs FP32; internal GEMMs bf16 MFMA (16x16x32).
// Pt layout: BLOCKED [b][qt][pt][128 q][128 p], tile = 32 KB contiguous.
// R14 = R12 + wconv (one-shot W fp32->bf16, blocked pre-swizzled) + proj
// W-path rebuilt as the proven gld_lds/dbuf/counted-vmcnt pipeline.

typedef __hip_bfloat16 bf16;
typedef __attribute__((ext_vector_type(8))) short bf16x8;   // 8 bf16 = 4 VGPRs
typedef __attribute__((ext_vector_type(4))) float f32x4;

#define AS1 __attribute__((address_space(1)))
#define AS3 __attribute__((address_space(3)))

__device__ __forceinline__ void gld_lds16(const bf16* g, bf16* s) {
    // async global->LDS, 16B/lane; LDS dst = wave-uniform base + lane*16
    __builtin_amdgcn_global_load_lds((const AS1 void*)g, (AS3 void*)s, 16, 0, 0);
}

// ---------------------------------------------------------------------------
// Kernel 0: one-shot W conversion. Wbf[m][kt][256 row][32 k], bf16,
// pre-swizzled (slot phys = sl ^ ((row>>1)&3)) so proj can stage slabs
// linearly via gld_lds and read fragments with the session-standard swizzle.
// m: 0=Wq 1=Wvi 2=Wk 3=Wvp (matches proj's widx = s*2+g).
// ---------------------------------------------------------------------------
__global__ __launch_bounds__(256) void wconv_kernel(
    const float* __restrict__ Wq, const float* __restrict__ Wvi,
    const float* __restrict__ Wk, const float* __restrict__ Wvp,
    bf16* __restrict__ Wbf)
{
    const int m  = blockIdx.x >> 3;                           // matrix 0..3
    const int kt = blockIdx.x & 7;                            // k-slab 0..7
    const float* W = (m == 0) ? Wq : (m == 1) ? Wvi : (m == 2) ? Wk : Wvp;
    bf16* D = Wbf + (size_t)(m * 8 + kt) * 8192;
    const int tid = threadIdx.x;
    for (int j = 0; j < 4; j++) {
        const int slot = j * 256 + tid;                       // 1024 8-elem slots
        const int row = slot >> 2, sl = slot & 3;
        const float4 a = *(const float4*)&W[row * 256 + kt * 32 + sl * 8];
        const float4 b = *(const float4*)&W[row * 256 + kt * 32 + sl * 8 + 4];
        bf16 t8[8];
        t8[0] = __float2bfloat16(a.x); t8[1] = __float2bfloat16(a.y);
        t8[2] = __float2bfloat16(a.z); t8[3] = __float2bfloat16(a.w);
        t8[4] = __float2bfloat16(b.x); t8[5] = __float2bfloat16(b.y);
        t8[6] = __float2bfloat16(b.z); t8[7] = __float2bfloat16(b.w);
        *(bf16x8*)&D[row * 32 + (sl ^ ((row >> 1) & 3)) * 8] = *(const bf16x8*)t8;
    }
}

// ---------------------------------------------------------------------------
// Kernel 1 (v5): projections. 512 blocks: blk = s*256 + b*128 + g*64 + ntile.
// W path rebuilt: bf16 pre-swizzled slabs staged via gld_lds (4 x 16B/thr/
// step), double-buffered, counted vmcnt(4) — clone of attn_s's proven loop.
// Replaces the old per-step {sync, 8 L2 fp32 loads + cvt + LDS write, sync}
// (serial, no overlap, W re-converted by 128 blocks each).
// Epilogues = R12 verbatim.
// ---------------------------------------------------------------------------
__global__ __launch_bounds__(256) void proj_kernel(
    const float* __restrict__ img, const float* __restrict__ pc,
    const bf16*  __restrict__ Wbf,
    const float* __restrict__ bq,  const float* __restrict__ bk,
    const float* __restrict__ bvi, const float* __restrict__ bvp,
    bf16* __restrict__ Qw, bf16* __restrict__ Ktw, bf16* __restrict__ Vall)
{
    __shared__ __align__(16) bf16 XT[64][264];    // [pos][cin], +8 pad (33 KB)
    __shared__ __align__(16) bf16 Wst[2][8192];   // dbuf W slab (32 KB)

    const int blk = blockIdx.x;
    const int s   = blk >> 8;
    const int b   = (blk >> 7) & 1;
    const int g   = (blk >> 6) & 1;
    const int n0  = (blk & 63) * 64;
    const int tid = threadIdx.x;

    if (s == 0) {
        const float* src = img + b * 1048576;                 // [256][4096]
        for (int k = 0; k < 16; k++) {
            const int i = tid + k * 256;
            const int cin = i >> 4, nl4 = (i & 15) * 4;
            const float4 v = *(const float4*)&src[cin * 4096 + n0 + nl4];
            XT[nl4 + 0][cin] = __float2bfloat16(v.x);
            XT[nl4 + 1][cin] = __float2bfloat16(v.y);
            XT[nl4 + 2][cin] = __float2bfloat16(v.z);
            XT[nl4 + 3][cin] = __float2bfloat16(v.w);
        }
    } else {
        // pc[b][d][h][w][c]: ch = c*16+d, flat = d*65536 + n*16 + c
        const float* src = pc + b * 1048576;
        for (int k = 0; k < 16; k++) {
            const int d = k, u = tid;
            const int nl = u >> 2, c4 = (u & 3) * 4;
            const float4 v = *(const float4*)&src[d * 65536 + (n0 + nl) * 16 + c4];
            XT[nl][(c4 + 0) * 16 + d] = __float2bfloat16(v.x);
            XT[nl][(c4 + 1) * 16 + d] = __float2bfloat16(v.y);
            XT[nl][(c4 + 2) * 16 + d] = __float2bfloat16(v.z);
            XT[nl][(c4 + 3) * 16 + d] = __float2bfloat16(v.w);
        }
    }
    __syncthreads();                                          // XT visible

    const int widx = s * 2 + g;                               // 0..3
    const bf16* Wp = Wbf + (size_t)widx * 65536 + tid * 8;
    const float* Bv = s ? (g ? bvp : bk) : (g ? bvi : bq);

    const int wv = tid >> 6, lane = tid & 63, l16 = lane & 15, quad = lane >> 4;
    const int ob = wv * 64;

    f32x4 acc[4][4] = {};

#define WSTAGE(buf, ks)                                                 \
    do {                                                                \
        const int _o = (ks) * 8192;                                     \
        bf16* _s = &Wst[(buf)][0];                                      \
        gld_lds16(Wp + _o,        _s + tid * 8);                        \
        gld_lds16(Wp + _o + 2048, _s + 2048 + tid * 8);                 \
        gld_lds16(Wp + _o + 4096, _s + 4096 + tid * 8);                 \
        gld_lds16(Wp + _o + 6144, _s + 6144 + tid * 8);                 \
    } while (0)

    WSTAGE(0, 0);
    int cur = 0;
    for (int ks = 0; ks < 8; ks++) {
        if (ks + 1 < 8) {
            WSTAGE(cur ^ 1, ks + 1);
            asm volatile("s_waitcnt vmcnt(4)" ::: "memory");  // cur's 4 landed
        } else {
            asm volatile("s_waitcnt vmcnt(0)" ::: "memory");
        }
        __builtin_amdgcn_s_barrier();                         // all waves' cur landed
        __builtin_amdgcn_sched_barrier(0);

        const int k0 = ks * 32;
        const bf16* Ws_ = &Wst[cur][0];
        bf16x8 af[4], wf[4];
        for (int ti = 0; ti < 4; ti++)
            af[ti] = *(const bf16x8*)&XT[ti * 16 + l16][k0 + quad * 8];
        for (int tj = 0; tj < 4; tj++) {
            const int rw = ob + tj * 16 + l16;
            wf[tj] = *(const bf16x8*)&Ws_[rw * 32 + (quad ^ ((rw >> 1) & 3)) * 8];
        }
        __builtin_amdgcn_s_setprio(1);
        for (int ti = 0; ti < 4; ti++)
            for (int tj = 0; tj < 4; tj++)
                acc[ti][tj] = __builtin_amdgcn_mfma_f32_16x16x32_bf16(af[ti], wf[tj], acc[ti][tj], 0, 0, 0);
        __builtin_amdgcn_s_setprio(0);

        asm volatile("s_waitcnt lgkmcnt(0)" ::: "memory");    // LDS reads retired
        __builtin_amdgcn_s_barrier();                         // safe to overwrite cur
        cur ^= 1;
    }
#undef WSTAGE

    if (g == 0) {
        bf16* D1 = (s ? Ktw : Qw) + b * (4096 * 256);          // [n][o]
        for (int tj = 0; tj < 4; tj++) {
            const int o = ob + tj * 16 + l16;
            const float bias = Bv[o];
            for (int ti = 0; ti < 4; ti++) {
                const int nl = ti * 16 + quad * 4;             // D row = quad*4+r
                for (int r = 0; r < 4; r++)
                    D1[(n0 + nl + r) * 256 + o] = __float2bfloat16(acc[ti][tj][r] + bias);
            }
        }
    } else {
        bf16* D2 = Vall + b * (512 * 4096) + (s ? 256 * 4096 : 0);  // [c'][p]
        for (int tj = 0; tj < 4; tj++) {
            const int o = ob + tj * 16 + l16;
            const float bias = Bv[o];
            for (int ti = 0; ti < 4; ti++) {
                const int nl = ti * 16 + quad * 4;
                bf16 pv[4];
                for (int r = 0; r < 4; r++)
                    pv[r] = __float2bfloat16(acc[ti][tj][r] + bias);
                *(uint2*)&D2[o * 4096 + n0 + nl] = *(const uint2*)pv;
            }
        }
    }
}

// ---------------------------------------------------------------------------
// Kernel 2 (v3): S^T tiles: A=Kt (p rows), B=Q (q rows), K=256.
// gld_lds + dbuf + counted vmcnt + XOR swizzle; blocked Pt store.
// ---------------------------------------------------------------------------
__global__ __launch_bounds__(256, 4) void attn_s_kernel(
    const bf16* __restrict__ Qw, const bf16* __restrict__ Ktw,
    bf16* __restrict__ Pt, float* __restrict__ Lpart)
{
    // per buffer: Kt-tile 128x32 @ 0 (8KB), Q-tile 128x32 @ 4096 (8KB)
    __shared__ __align__(16) bf16 smem[2][8192];              // 32 KB

    const int b  = blockIdx.z;
    const int q0 = blockIdx.y * 128;
    const int p0 = blockIdx.x * 128;
    const bf16* Aq = Qw  + b * (4096 * 256);
    const bf16* Ak = Ktw + b * (4096 * 256);

    const int tid = threadIdx.x;
    const int wv = tid >> 6, lane = tid & 63, l16 = lane & 15, quad = lane >> 4;
    const int wr = wv >> 1, wc = wv & 1;                      // wr: p-half, wc: q-half

    // swizzled fragment-read offsets (bf16 units), constant over ks
    int aoff[4], boff[4];
    for (int t = 0; t < 4; t++) {
        const int rowa = wr * 64 + t * 16 + l16;              // p row
        aoff[t] = rowa * 32 + (quad ^ ((rowa >> 1) & 3)) * 8;
        const int rowb = wc * 64 + t * 16 + l16;              // q row
        boff[t] = rowb * 32 + (quad ^ ((rowb >> 1) & 3)) * 8;
    }

    // staging: 512 16B-slots per tile; thread t covers slots t and t+256
    const int arow0 = tid >> 2;                               // rows 0..63
    const int kswz = ((tid & 3) ^ ((arow0 >> 1) & 3)) * 8;    // same for row+64
    const bf16* Ag0 = Ak + (p0 + arow0) * 256 + kswz;
    const bf16* Ag1 = Ak + (p0 + 64 + arow0) * 256 + kswz;
    const bf16* Bg0 = Aq + (q0 + arow0) * 256 + kswz;
    const bf16* Bg1 = Aq + (q0 + 64 + arow0) * 256 + kswz;

    f32x4 acc[4][4] = {};

#define SSTAGE(buf, ks)                                                 \
    do {                                                                \
        const int _k = (ks) * 32;                                       \
        bf16* _s = &smem[(buf)][0];                                     \
        gld_lds16(Ag0 + _k, _s + tid * 8);                              \
        gld_lds16(Ag1 + _k, _s + 2048 + tid * 8);                       \
        gld_lds16(Bg0 + _k, _s + 4096 + tid * 8);                       \
        gld_lds16(Bg1 + _k, _s + 6144 + tid * 8);                       \
    } while (0)

    SSTAGE(0, 0);
    int cur = 0;
    for (int ks = 0; ks < 8; ks++) {
        if (ks + 1 < 8) {
            SSTAGE(cur ^ 1, ks + 1);
            asm volatile("s_waitcnt vmcnt(4)" ::: "memory");  // cur's 4 landed
        } else {
            asm volatile("s_waitcnt vmcnt(0)" ::: "memory");
        }
        __builtin_amdgcn_s_barrier();                         // all waves' cur landed
        __builtin_amdgcn_sched_barrier(0);

        const bf16* As_ = &smem[cur][0];
        const bf16* Bs_ = &smem[cur][4096];
        bf16x8 af[4], bfr[4];
        for (int t = 0; t < 4; t++) af[t]  = *(const bf16x8*)&As_[aoff[t]];
        for (int t = 0; t < 4; t++) bfr[t] = *(const bf16x8*)&Bs_[boff[t]];
        __builtin_amdgcn_s_setprio(1);
        for (int ti = 0; ti < 4; ti++)
            for (int tj = 0; tj < 4; tj++)
                acc[ti][tj] = __builtin_amdgcn_mfma_f32_16x16x32_bf16(af[ti], bfr[tj], acc[ti][tj], 0, 0, 0);
        __builtin_amdgcn_s_setprio(0);

        asm volatile("s_waitcnt lgkmcnt(0)" ::: "memory");    // LDS reads retired
        __builtin_amdgcn_s_barrier();                         // safe to overwrite cur
        cur ^= 1;
    }
#undef SSTAGE

    __syncthreads();                                          // staging done; reuse LDS

    // ---- exp + LDS transpose (swizzled [128 q][128 p]) + L-partials ----
    bf16* T = &smem[0][0];                                    // 16384 bf16 = 32 KB
    const int strip = blockIdx.x * 2 + wr;                    // p strip of 64
    for (int tj = 0; tj < 4; tj++) {
        const int ql = wc * 64 + tj * 16 + l16;               // local q
        const int sw = (ql & 7) << 3;
        float partial = 0.0f;
        for (int ti = 0; ti < 4; ti++) {
            const int pb = wr * 64 + ti * 16 + quad * 4;      // local p base
            bf16 pv[4];
            for (int r = 0; r < 4; r++) {
                const float e = __expf(fminf(acc[ti][tj][r], 80.0f));
                partial += e;
                pv[r] = __float2bfloat16(e);
            }
            *(uint2*)&T[ql * 128 + (pb ^ sw)] = *(const uint2*)pv;
        }
        partial += __shfl_xor(partial, 16);
        partial += __shfl_xor(partial, 32);
        if (lane < 16)
            Lpart[(size_t)(b * 4096 + q0 + ql) * 64 + strip] = partial;
    }
    __syncthreads();

    // ---- coalesced blocked store: tile 32 KB contiguous ----
    bf16* Ptile = Pt + (size_t)((b * 32 + (q0 >> 7)) * 32 + (p0 >> 7)) * 16384;
    for (int j = 0; j < 8; j++) {
        const int qr = wv * 32 + j * 4 + (lane >> 4);         // local q row
        const int pcm = (lane & 15) * 8;                      // local p chunk
        const bf16x8 v = *(const bf16x8*)&T[qr * 128 + (pcm ^ ((qr & 7) << 3))];
        *(bf16x8*)&Ptile[qr * 128 + pcm] = v;                 // 1KB contig/instr
    }
}

// ---------------------------------------------------------------------------
// Kernel 2b: Linv[b][q] = 1 / sum_strip Lpart  (8192 rows)
// ---------------------------------------------------------------------------
__global__ __launch_bounds__(256) void lred_kernel(
    const float* __restrict__ Lpart, float* __restrict__ Linv)
{
    const int row = blockIdx.x * 256 + threadIdx.x;           // [0, 8192)
    const float4* lp = (const float4*)&Lpart[(size_t)row * 64];
    float s = 0.0f;
    for (int i = 0; i < 16; i++) {
        const float4 v = lp[i];
        s += v.x + v.y + v.z + v.w;
    }
    Linv[row] = 1.0f / fmaxf(s, 1e-30f);
}

// ---------------------------------------------------------------------------
// Kernel 3 (v7): O = Vall.Pt^T (NT, K=4096) * Linv[q].
// 128c x 128q, 256 blocks, 2 K-groups, quad-buffered counted-vmcnt pipeline,
// XOR + XCD swizzles, blocked-Pt B reads, deterministic combine.
// ---------------------------------------------------------------------------
__global__ __launch_bounds__(512, 2) void attn_o_kernel(
    const bf16* __restrict__ Vall, const bf16* __restrict__ Pt,
    const float* __restrict__ Linv, float* __restrict__ out)
{
    // [grp][buf]: As 128x32 @ 0 (4096 elems), Bs 128x32 @ 4096
    __shared__ __align__(16) bf16 smem[2][4][8192];           // 128 KB

    const int orig = blockIdx.x;
    const int L = (orig & 7) * 32 + (orig >> 3);              // XCD chunk swizzle
    const int b   = L >> 7;
    const int rem = L & 127;
    const int c0  = (rem & 3) * 128;
    const int q0  = (rem >> 2) * 128;

    const bf16* A  = Vall + (size_t)b * 512 * 4096;
    const bf16* Bt = Pt + (size_t)((b * 32 + (q0 >> 7)) * 32) * 16384;

    const int tid = threadIdx.x;
    const int grp = tid >> 8;                                 // K-split group (2)
    const int t8  = tid & 255;
    const int wv = t8 >> 6, lane = t8 & 63, l16 = lane & 15, quad = lane >> 4;
    const int wr = wv >> 1, wc = wv & 1;                      // 64c x 64q wave tile

    // swizzled fragment-read offsets (bf16 units), constant over ks
    int aoff[4], boff[4];
    for (int t = 0; t < 4; t++) {
        const int rowa = wr * 64 + t * 16 + l16;
        aoff[t] = rowa * 32 + (quad ^ ((rowa >> 1) & 3)) * 8;
        const int rowb = wc * 64 + t * 16 + l16;
        boff[t] = rowb * 32 + (quad ^ ((rowb >> 1) & 3)) * 8;
    }

    const int arow = t8 >> 2;                                 // staged row (local)
    const int kswz = ((t8 & 3) ^ ((arow >> 1) & 3)) * 8;      // pre-swizzled k chunk
    const bf16* Ag0 = A + (c0 + arow) * 4096 + kswz;
    const bf16* Ag1 = A + (c0 + 64 + arow) * 4096 + kswz;

    f32x4 acc[4][4] = {};

#define STAGE(buf, ks)                                                  \
    do {                                                                \
        const int _kk = grp * 2048 + (ks) * 32;                         \
        bf16* _s = &smem[grp][(buf)][0];                                \
        gld_lds16(Ag0 + _kk, _s + t8 * 8);                              \
        gld_lds16(Ag1 + _kk, _s + 2048 + t8 * 8);                       \
        const bf16* _bp = Bt + (size_t)(_kk >> 7) * 16384               \
                          + arow * 128 + (_kk & 127) + kswz;            \
        gld_lds16(_bp, _s + 4096 + t8 * 8);                             \
        gld_lds16(_bp + 8192, _s + 6144 + t8 * 8);                      \
    } while (0)

    STAGE(0, 0);
    STAGE(1, 1);
    STAGE(2, 2);
    for (int ks = 0; ks < 64; ks++) {
        // depth-4 counted prefetch: consumed stage ks was issued 3 iters ago
        if (ks + 3 < 64) {
            STAGE((ks + 3) & 3, ks + 3);
            asm volatile("s_waitcnt vmcnt(12)" ::: "memory"); // stage ks landed
        } else if (ks + 2 < 64) {
            asm volatile("s_waitcnt vmcnt(8)" ::: "memory");
        } else if (ks + 1 < 64) {
            asm volatile("s_waitcnt vmcnt(4)" ::: "memory");
        } else {
            asm volatile("s_waitcnt vmcnt(0)" ::: "memory");
        }
        __builtin_amdgcn_s_barrier();                         // all waves' stage ks landed
        __builtin_amdgcn_sched_barrier(0);

        const bf16* As_ = &smem[grp][ks & 3][0];
        const bf16* Bs_ = &smem[grp][ks & 3][4096];
        bf16x8 af[4], bfr[4];
        for (int t = 0; t < 4; t++) af[t]  = *(const bf16x8*)&As_[aoff[t]];
        for (int t = 0; t < 4; t++) bfr[t] = *(const bf16x8*)&Bs_[boff[t]];
        __builtin_amdgcn_s_setprio(1);
        for (int ti = 0; ti < 4; ti++)
            for (int tj = 0; tj < 4; tj++)
                acc[ti][tj] = __builtin_amdgcn_mfma_f32_16x16x32_bf16(af[ti], bfr[tj], acc[ti][tj], 0, 0, 0);
        __builtin_amdgcn_s_setprio(0);

        asm volatile("s_waitcnt lgkmcnt(0)" ::: "memory");    // LDS reads retired
        __builtin_amdgcn_s_barrier();                         // safe to overwrite buf (ks+4)&3
    }
#undef STAGE

    __syncthreads();                                          // full fence before LDS reuse

    // Deterministic cross-group combine in LDS (reuses staging space).
    float* comb = (float*)&smem[0][0][0];                     // [128 c][128 q] fp32 = 64 KB
    if (grp == 0) {
        for (int ti = 0; ti < 4; ti++)
            for (int tj = 0; tj < 4; tj++)
                for (int r = 0; r < 4; r++)
                    comb[(wr * 64 + ti * 16 + quad * 4 + r) * 128 + wc * 64 + tj * 16 + l16]
                        = acc[ti][tj][r];
    }
    __syncthreads();
    if (grp == 1) {
        for (int ti = 0; ti < 4; ti++)
            for (int tj = 0; tj < 4; tj++)
                for (int r = 0; r < 4; r++)
                    comb[(wr * 64 + ti * 16 + quad * 4 + r) * 128 + wc * 64 + tj * 16 + l16]
                        += acc[ti][tj][r];
    }
    __syncthreads();

    // All 512 threads: scale by Linv[q], store one c-row x 32 q segment.
    const int cl = tid >> 2, qb = (tid & 3) * 32;
    const int c_ = c0 + cl;
    const size_t base = (c_ < 256)
        ? ((size_t)b * 1048576 + (size_t)c_ * 4096)
        : (2097152u + (size_t)b * 1048576 + (size_t)(c_ - 256) * 4096);
    for (int j = 0; j < 8; j++) {
        const float4 v = *(const float4*)&comb[cl * 128 + qb + j * 4];
        const float4 l = *(const float4*)&Linv[b * 4096 + q0 + qb + j * 4];
        float4 o;
        o.x = v.x * l.x; o.y = v.y * l.y; o.z = v.z * l.z; o.w = v.w * l.w;
        *(float4*)&out[base + q0 + qb + j * 4] = o;
    }
}

// ---------------------------------------------------------------------------
// ws: [0,4)MB Q | [4,8)MB Kt | [8,16)MB Vall | [16,80)MB Pt (blocked) |
//     [80,82)MB Lpart fp32 [2][4096][64] | [82MB,+32KB) Linv fp32 [2][4096] |
//     [83MB,+512KB) Wbf bf16 [4][8][256][32] pre-swizzled
// ---------------------------------------------------------------------------
extern "C" void kernel_launch(void* const* d_in, const int* in_sizes, int n_in,
                              void* d_out, int out_size, void* d_ws, size_t ws_size,
                              hipStream_t stream)
{
    const float* img = (const float*)d_in[0];
    const float* pc  = (const float*)d_in[1];
    const float* Wq  = (const float*)d_in[2];
    const float* bq  = (const float*)d_in[3];
    const float* Wk  = (const float*)d_in[4];
    const float* bk  = (const float*)d_in[5];
    const float* Wvi = (const float*)d_in[6];
    const float* bvi = (const float*)d_in[7];
    const float* Wvp = (const float*)d_in[8];
    const float* bvp = (const float*)d_in[9];

    char* ws = (char*)d_ws;
    bf16*  Qw    = (bf16*)(ws);
    bf16*  Ktw   = (bf16*)(ws + (4ull  << 20));
    bf16*  Vall  = (bf16*)(ws + (8ull  << 20));
    bf16*  Pt    = (bf16*)(ws + (16ull << 20));
    float* Lpart = (float*)(ws + (80ull << 20));
    float* Linv  = (float*)(ws + (82ull << 20));
    bf16*  Wbf   = (bf16*)(ws + (83ull << 20));

    wconv_kernel<<<32, 256, 0, stream>>>(Wq, Wvi, Wk, Wvp, Wbf);
    proj_kernel<<<512, 256, 0, stream>>>(img, pc, Wbf, bq, bk, bvi, bvp,
                                         Qw, Ktw, Vall);
    attn_s_kernel<<<dim3(32, 32, 2), 256, 0, stream>>>(Qw, Ktw, Pt, Lpart);
    lred_kernel<<<32, 256, 0, stream>>>(Lpart, Linv);
    attn_o_kernel<<<256, 512, 0, stream>>>(Vall, Pt, Linv, (float*)d_out);
}